// Round 1
// baseline (248.453 us; speedup 1.0000x reference)
//
#include <hip/hip_runtime.h>

#define BN_EPS 1e-5f

typedef unsigned short u16;
typedef __bf16 bf16x8 __attribute__((ext_vector_type(8)));
typedef float floatx4 __attribute__((ext_vector_type(4)));
typedef u16 u16x8 __attribute__((ext_vector_type(8)));

__device__ __forceinline__ u16 f2bf(float f) {
    union { float f; unsigned int u; } v; v.f = f;
    unsigned int r = (v.u + 0x7fffu + ((v.u >> 16) & 1u)) >> 16;
    return (u16)r;
}

// ---------------------------------------------------------------- prep ----
// Fold BN scale into conv weights (fp32), cast to bf16; emit shift (bias).
__global__ __launch_bounds__(256) void prep_kernel(
    const float* __restrict__ wt, const float* __restrict__ wp,
    const float* __restrict__ wg, const float* __restrict__ wz,
    const float* __restrict__ g1, const float* __restrict__ b1,
    const float* __restrict__ m1, const float* __restrict__ v1,
    const float* __restrict__ g2, const float* __restrict__ b2,
    const float* __restrict__ m2, const float* __restrict__ v2,
    const float* __restrict__ g3, const float* __restrict__ b3,
    const float* __restrict__ m3, const float* __restrict__ v3,
    const float* __restrict__ g4, const float* __restrict__ b4,
    const float* __restrict__ m4, const float* __restrict__ v4,
    u16* __restrict__ W1bf, float* __restrict__ shift1,
    u16* __restrict__ Wzbf, float* __restrict__ shift4)
{
    int id = blockIdx.x * 256 + threadIdx.x;
    if (id < 384 * 256) {
        int r = id >> 8, c = id & 255;
        int grp = r >> 7, ch = r & 127;
        const float* wsrc = grp == 0 ? wt : (grp == 1 ? wp : wg);
        const float* gg = grp == 0 ? g1 : (grp == 1 ? g2 : g3);
        const float* bb = grp == 0 ? b1 : (grp == 1 ? b2 : b3);
        const float* mm = grp == 0 ? m1 : (grp == 1 ? m2 : m3);
        const float* vv = grp == 0 ? v1 : (grp == 1 ? v2 : v3);
        float scale = gg[ch] * rsqrtf(vv[ch] + BN_EPS);
        W1bf[id] = f2bf(wsrc[ch * 256 + c] * scale);
        if (c == 0) shift1[r] = bb[ch] - mm[ch] * scale;
    }
    if (id < 256 * 128) {
        int o = id >> 7, c2 = id & 127;
        float scale = g4[o] * rsqrtf(v4[o] + BN_EPS);
        Wzbf[id] = f2bf(wz[id] * scale);
        if (c2 == 0) shift4[o] = b4[o] - m4[o] * scale;
    }
}

// --------------------------------------------------------------- gemm1 ----
// tpg[n][oc][s] = relu( sum_c W1[oc][c] * x[n][c][s] + shift1[oc] ), oc<384
// M=384 (3 tiles of 128), N=4096 (32 tiles of 128), K=256 (2 LDS chunks of 128)
__global__ __launch_bounds__(256) void gemm1_kernel(
    const float* __restrict__ x, const u16* __restrict__ W1,
    const float* __restrict__ shift1, u16* __restrict__ tpg)
{
    const int st = blockIdx.x;   // s tile 0..31
    const int mt = blockIdx.y;   // oc tile 0..2
    const int n  = blockIdx.z;   // 0..15
    const int tid = threadIdx.x;
    const int wave = tid >> 6, lane = tid & 63;
    const int quad = lane >> 4, l16 = lane & 15;

    __shared__ __align__(16) u16 ldsX[128 * 136];   // [s][c_chunk] padded

    floatx4 acc[2][8];
#pragma unroll
    for (int i = 0; i < 2; ++i)
#pragma unroll
        for (int j = 0; j < 8; ++j) acc[i][j] = floatx4{0.f, 0.f, 0.f, 0.f};

    const int cl = tid & 127;
    const int hv = tid >> 7;

    for (int kc = 0; kc < 2; ++kc) {
        if (kc) __syncthreads();
        // stage x[n][kc*128+cl][st*128 + hv*64 .. +64] -> ldsX[s][cl] (transpose, bf16)
        const float* xp = x + (((size_t)n * 256 + kc * 128 + cl) * 4096) + st * 128 + hv * 64;
        const float4* xp4 = reinterpret_cast<const float4*>(xp);
#pragma unroll
        for (int i = 0; i < 16; ++i) {
            float4 v = xp4[i];
            int s0 = hv * 64 + i * 4;
            ldsX[(s0 + 0) * 136 + cl] = f2bf(v.x);
            ldsX[(s0 + 1) * 136 + cl] = f2bf(v.y);
            ldsX[(s0 + 2) * 136 + cl] = f2bf(v.z);
            ldsX[(s0 + 3) * 136 + cl] = f2bf(v.w);
        }
        __syncthreads();

#pragma unroll
        for (int kk = 0; kk < 4; ++kk) {
            bf16x8 a[2];
#pragma unroll
            for (int mi = 0; mi < 2; ++mi) {
                int oc = mt * 128 + wave * 32 + mi * 16 + l16;
                a[mi] = *reinterpret_cast<const bf16x8*>(
                    W1 + (size_t)oc * 256 + kc * 128 + kk * 32 + quad * 8);
            }
#pragma unroll
            for (int ni = 0; ni < 8; ++ni) {
                int sl = ni * 16 + l16;
                bf16x8 b = *reinterpret_cast<const bf16x8*>(
                    &ldsX[sl * 136 + kk * 32 + quad * 8]);
#pragma unroll
                for (int mi = 0; mi < 2; ++mi)
                    acc[mi][ni] = __builtin_amdgcn_mfma_f32_16x16x32_bf16(
                        a[mi], b, acc[mi][ni], 0, 0, 0);
            }
        }
    }

#pragma unroll
    for (int mi = 0; mi < 2; ++mi) {
#pragma unroll
        for (int r = 0; r < 4; ++r) {
            int oc = mt * 128 + wave * 32 + mi * 16 + quad * 4 + r;
            float sh = shift1[oc];
#pragma unroll
            for (int ni = 0; ni < 8; ++ni) {
                int s = st * 128 + ni * 16 + l16;
                float val = acc[mi][ni][r] + sh;
                val = val > 0.f ? val : 0.f;
                tpg[((size_t)n * 384 + oc) * 4096 + s] = f2bf(val);
            }
        }
    }
}

// --------------------------------------------------------------- gemm2 ----
// partials[n][kc][d][c] = sum_{s in chunk} g[d][s]*phi[c][s]   (split-K=16)
__global__ __launch_bounds__(256) void gemm2_kernel(
    const u16* __restrict__ tpg, float* __restrict__ partials)
{
    const int kc = blockIdx.x;   // 0..15
    const int n  = blockIdx.y;
    const int tid = threadIdx.x;
    const int wave = tid >> 6, lane = tid & 63;
    const int quad = lane >> 4, l16 = lane & 15;

    floatx4 acc[2][8];
#pragma unroll
    for (int i = 0; i < 2; ++i)
#pragma unroll
        for (int j = 0; j < 8; ++j) acc[i][j] = floatx4{0.f, 0.f, 0.f, 0.f};

    const u16* gbase = tpg + ((size_t)n * 384 + 256) * 4096;  // g rows
    const u16* pbase = tpg + ((size_t)n * 384 + 128) * 4096;  // phi rows

#pragma unroll
    for (int kk = 0; kk < 8; ++kk) {
        int sb = kc * 256 + kk * 32 + quad * 8;
        bf16x8 a[2];
#pragma unroll
        for (int mi = 0; mi < 2; ++mi) {
            int d = wave * 32 + mi * 16 + l16;
            a[mi] = *reinterpret_cast<const bf16x8*>(gbase + (size_t)d * 4096 + sb);
        }
#pragma unroll
        for (int ci = 0; ci < 8; ++ci) {
            int cc = ci * 16 + l16;
            bf16x8 b = *reinterpret_cast<const bf16x8*>(pbase + (size_t)cc * 4096 + sb);
#pragma unroll
            for (int mi = 0; mi < 2; ++mi)
                acc[mi][ci] = __builtin_amdgcn_mfma_f32_16x16x32_bf16(
                    a[mi], b, acc[mi][ci], 0, 0, 0);
        }
    }

    float* outp = partials + (size_t)(n * 16 + kc) * 16384;
#pragma unroll
    for (int mi = 0; mi < 2; ++mi)
#pragma unroll
        for (int r = 0; r < 4; ++r) {
            int d = wave * 32 + mi * 16 + quad * 4 + r;
#pragma unroll
            for (int ci = 0; ci < 8; ++ci)
                outp[d * 128 + ci * 16 + l16] = acc[mi][ci][r];
        }
}

// ----------------------------------------------------------- kv reduce ----
__global__ __launch_bounds__(256) void kv_reduce_kernel(
    const float* __restrict__ partials, u16* __restrict__ kvT)
{
    int n = blockIdx.y;
    int idx = blockIdx.x * 256 + threadIdx.x;   // 0..16383
    float s = 0.f;
#pragma unroll
    for (int kc = 0; kc < 16; ++kc)
        s += partials[(size_t)(n * 16 + kc) * 16384 + idx];
    kvT[(size_t)n * 16384 + idx] = f2bf(s);
}

// --------------------------------------------------------------- gemm3 ----
// out_sd[n][s][d] = sum_c theta[c][s] * kvT[d][c]
__global__ __launch_bounds__(256) void gemm3_kernel(
    const u16* __restrict__ tpg, const u16* __restrict__ kvT,
    u16* __restrict__ out_sd)
{
    const int st = blockIdx.x;   // 0..31
    const int n  = blockIdx.y;
    const int tid = threadIdx.x;
    const int wave = tid >> 6, lane = tid & 63;
    const int quad = lane >> 4, l16 = lane & 15;

    __shared__ __align__(16) u16 ldsA[128 * 136];   // [s][c] (theta transposed)

    const int cl = tid & 127;
    const int hv = tid >> 7;
    const u16* tp = tpg + ((size_t)n * 384 + cl) * 4096 + st * 128 + hv * 64;
    const u16x8* tp8 = reinterpret_cast<const u16x8*>(tp);
#pragma unroll
    for (int i = 0; i < 8; ++i) {
        u16x8 v = tp8[i];
        int s0 = hv * 64 + i * 8;
#pragma unroll
        for (int j = 0; j < 8; ++j) ldsA[(s0 + j) * 136 + cl] = v[j];
    }
    __syncthreads();

    floatx4 acc[2][8];
#pragma unroll
    for (int i = 0; i < 2; ++i)
#pragma unroll
        for (int j = 0; j < 8; ++j) acc[i][j] = floatx4{0.f, 0.f, 0.f, 0.f};

    const u16* kvb = kvT + (size_t)n * 16384;
#pragma unroll
    for (int kk = 0; kk < 4; ++kk) {
        bf16x8 a[2];
#pragma unroll
        for (int mi = 0; mi < 2; ++mi) {
            int m = wave * 32 + mi * 16 + l16;
            a[mi] = *reinterpret_cast<const bf16x8*>(&ldsA[m * 136 + kk * 32 + quad * 8]);
        }
#pragma unroll
        for (int di = 0; di < 8; ++di) {
            int d = di * 16 + l16;
            bf16x8 b = *reinterpret_cast<const bf16x8*>(kvb + d * 128 + kk * 32 + quad * 8);
#pragma unroll
            for (int mi = 0; mi < 2; ++mi)
                acc[mi][di] = __builtin_amdgcn_mfma_f32_16x16x32_bf16(
                    a[mi], b, acc[mi][di], 0, 0, 0);
        }
    }

#pragma unroll
    for (int mi = 0; mi < 2; ++mi)
#pragma unroll
        for (int r = 0; r < 4; ++r) {
            int s = st * 128 + wave * 32 + mi * 16 + quad * 4 + r;
#pragma unroll
            for (int di = 0; di < 8; ++di) {
                int d = di * 16 + l16;
                out_sd[((size_t)n * 4096 + s) * 128 + d] = f2bf(acc[mi][di][r]);
            }
        }
}

// --------------------------------------------------------------- gemm4 ----
// out[n][o][s2] = relu( sum_c2 Wz[o][c2]*y[c2][s2] + shift4[o] + x[n][o][s2] )
// where y[c2][s2] = out_sd viewed flat (the torch reshape scramble).
__global__ __launch_bounds__(256) void gemm4_kernel(
    const u16* __restrict__ out_sd, const u16* __restrict__ Wz,
    const float* __restrict__ shift4, const float* __restrict__ x,
    float* __restrict__ out)
{
    const int st = blockIdx.x;   // 0..31
    const int ot = blockIdx.y;   // 0..1
    const int n  = blockIdx.z;
    const int tid = threadIdx.x;
    const int wave = tid >> 6, lane = tid & 63;
    const int quad = lane >> 4, l16 = lane & 15;

    __shared__ __align__(16) u16 ldsY[128 * 136];   // [s2][c2] (y transposed)

    const int cl = tid & 127;
    const int hv = tid >> 7;
    const u16* yp = out_sd + (size_t)n * 524288 + (size_t)cl * 4096 + st * 128 + hv * 64;
    const u16x8* yp8 = reinterpret_cast<const u16x8*>(yp);
#pragma unroll
    for (int i = 0; i < 8; ++i) {
        u16x8 v = yp8[i];
        int s0 = hv * 64 + i * 8;
#pragma unroll
        for (int j = 0; j < 8; ++j) ldsY[(s0 + j) * 136 + cl] = v[j];
    }
    __syncthreads();

    floatx4 acc[2][8];
#pragma unroll
    for (int i = 0; i < 2; ++i)
#pragma unroll
        for (int j = 0; j < 8; ++j) acc[i][j] = floatx4{0.f, 0.f, 0.f, 0.f};

#pragma unroll
    for (int kk = 0; kk < 4; ++kk) {
        bf16x8 a[2];
#pragma unroll
        for (int mi = 0; mi < 2; ++mi) {
            int o = ot * 128 + wave * 32 + mi * 16 + l16;
            a[mi] = *reinterpret_cast<const bf16x8*>(Wz + (size_t)o * 128 + kk * 32 + quad * 8);
        }
#pragma unroll
        for (int ni = 0; ni < 8; ++ni) {
            int s2l = ni * 16 + l16;
            bf16x8 b = *reinterpret_cast<const bf16x8*>(&ldsY[s2l * 136 + kk * 32 + quad * 8]);
#pragma unroll
            for (int mi = 0; mi < 2; ++mi)
                acc[mi][ni] = __builtin_amdgcn_mfma_f32_16x16x32_bf16(
                    a[mi], b, acc[mi][ni], 0, 0, 0);
        }
    }

#pragma unroll
    for (int mi = 0; mi < 2; ++mi)
#pragma unroll
        for (int r = 0; r < 4; ++r) {
            int o = ot * 128 + wave * 32 + mi * 16 + quad * 4 + r;
            float sh = shift4[o];
#pragma unroll
            for (int ni = 0; ni < 8; ++ni) {
                int s2 = st * 128 + ni * 16 + l16;
                size_t idx = ((size_t)n * 256 + o) * 4096 + s2;
                float val = acc[mi][ni][r] + sh + x[idx];
                out[idx] = val > 0.f ? val : 0.f;
            }
        }
}

// -------------------------------------------------------------- launch ----
extern "C" void kernel_launch(void* const* d_in, const int* in_sizes, int n_in,
                              void* d_out, int out_size, void* d_ws, size_t ws_size,
                              hipStream_t stream)
{
    const float* x  = (const float*)d_in[0];
    const float* wt = (const float*)d_in[1];
    const float* wp = (const float*)d_in[2];
    const float* wg = (const float*)d_in[3];
    const float* wz = (const float*)d_in[4];
    const float* bn[16];
    for (int i = 0; i < 16; ++i) bn[i] = (const float*)d_in[5 + i];

    char* ws = (char*)d_ws;
    // ws layout (all offsets 256B aligned):
    u16*   W1bf     = (u16*)  (ws + 0);          //   384*256*2   = 196608
    float* shift1   = (float*)(ws + 196608);     //   384*4       = 1536
    u16*   Wzbf     = (u16*)  (ws + 198144);     //   256*128*2   = 65536
    float* shift4   = (float*)(ws + 263680);     //   256*4       = 1024
    u16*   tpg      = (u16*)  (ws + 264704);     //   16*384*4096*2 = 50331648
    float* partials = (float*)(ws + 50596352);   //   16*16*16384*4 = 16777216
    u16*   kvT      = (u16*)  (ws + 67373568);   //   16*16384*2  = 524288
    u16*   out_sd   = (u16*)  (ws + 67897856);   //   16*4096*128*2 = 16777216
    float* out = (float*)d_out;                  //   total ws use ~80.8 MiB

    prep_kernel<<<384, 256, 0, stream>>>(
        wt, wp, wg, wz,
        bn[0], bn[1], bn[2], bn[3],
        bn[4], bn[5], bn[6], bn[7],
        bn[8], bn[9], bn[10], bn[11],
        bn[12], bn[13], bn[14], bn[15],
        W1bf, shift1, Wzbf, shift4);

    gemm1_kernel<<<dim3(32, 3, 16), 256, 0, stream>>>(x, W1bf, shift1, tpg);
    gemm2_kernel<<<dim3(16, 16), 256, 0, stream>>>(tpg, partials);
    kv_reduce_kernel<<<dim3(64, 16), 256, 0, stream>>>(partials, kvT);
    gemm3_kernel<<<dim3(32, 16), 256, 0, stream>>>(tpg, kvT, out_sd);
    gemm4_kernel<<<dim3(32, 2, 16), 256, 0, stream>>>(out_sd, Wzbf, shift4, x, out);
}

// Round 2
// 228.559 us; speedup vs baseline: 1.0870x; 1.0870x over previous
//
#include <hip/hip_runtime.h>

#define BN_EPS 1e-5f

typedef unsigned short u16;
typedef __bf16 bf16x8 __attribute__((ext_vector_type(8)));
typedef float floatx4 __attribute__((ext_vector_type(4)));
typedef u16 u16x8 __attribute__((ext_vector_type(8)));

__device__ __forceinline__ u16 f2bf(float f) {
    union { float f; unsigned int u; } v; v.f = f;
    unsigned int r = (v.u + 0x7fffu + ((v.u >> 16) & 1u)) >> 16;
    return (u16)r;
}

// async 16B global->LDS. Data for lane i lands at (wave-uniform) dst + i*16.
__device__ __forceinline__ void gld16(const void* gsrc, void* ldst) {
    __builtin_amdgcn_global_load_lds(
        (const __attribute__((address_space(1))) unsigned int*)gsrc,
        (__attribute__((address_space(3))) unsigned int*)ldst, 16, 0, 0);
}

// additive seg swizzle for transpose-staged [row][64] u16 tiles
__device__ __forceinline__ int addsw(int seg, int s) {
    return (seg + (s & 7) + ((s >> 3) & 7)) & 7;
}

// ---------------------------------------------------------------- prep ----
__global__ __launch_bounds__(256) void prep_kernel(
    const float* __restrict__ wt, const float* __restrict__ wp,
    const float* __restrict__ wg, const float* __restrict__ wz,
    const float* __restrict__ g1, const float* __restrict__ b1,
    const float* __restrict__ m1, const float* __restrict__ v1,
    const float* __restrict__ g2, const float* __restrict__ b2,
    const float* __restrict__ m2, const float* __restrict__ v2,
    const float* __restrict__ g3, const float* __restrict__ b3,
    const float* __restrict__ m3, const float* __restrict__ v3,
    const float* __restrict__ g4, const float* __restrict__ b4,
    const float* __restrict__ m4, const float* __restrict__ v4,
    u16* __restrict__ W1bf, float* __restrict__ shift1,
    u16* __restrict__ Wzbf, float* __restrict__ shift4)
{
    int id = blockIdx.x * 256 + threadIdx.x;
    if (id < 384 * 256) {
        int r = id >> 8, c = id & 255;
        int grp = r >> 7, ch = r & 127;
        const float* wsrc = grp == 0 ? wt : (grp == 1 ? wp : wg);
        const float* gg = grp == 0 ? g1 : (grp == 1 ? g2 : g3);
        const float* bb = grp == 0 ? b1 : (grp == 1 ? b2 : b3);
        const float* mm = grp == 0 ? m1 : (grp == 1 ? m2 : m3);
        const float* vv = grp == 0 ? v1 : (grp == 1 ? v2 : v3);
        float scale = gg[ch] * rsqrtf(vv[ch] + BN_EPS);
        W1bf[id] = f2bf(wsrc[ch * 256 + c] * scale);
        if (c == 0) shift1[r] = bb[ch] - mm[ch] * scale;
    }
    if (id < 256 * 128) {
        int o = id >> 7;
        float scale = g4[o] * rsqrtf(v4[o] + BN_EPS);
        Wzbf[id] = f2bf(wz[id] * scale);
        if ((id & 127) == 0) shift4[o] = b4[o] - m4[o] * scale;
    }
}

// --------------------------------------------------------------- gemm1 ----
// tpg[n][oc][s] = relu( sum_c W1[oc][c]*x[n][c][s] + shift1[oc] )
// tile 128oc x 128s, K=256 in 4 chunks of 64.
__global__ __launch_bounds__(256) void gemm1_kernel(
    const float* __restrict__ x, const u16* __restrict__ W1,
    const float* __restrict__ shift1, u16* __restrict__ tpg)
{
    const int st = blockIdx.x, mt = blockIdx.y, n = blockIdx.z;
    const int tid = threadIdx.x;
    const int w = tid >> 6, lane = tid & 63;
    const int quad = lane >> 4, l16 = lane & 15;

    __shared__ __align__(16) u16 ldsA[128 * 64];  // W1 chunk, xor-swizzled
    __shared__ __align__(16) u16 ldsB[128 * 64];  // x^T chunk [s][c], add-swizzled

    floatx4 acc[2][8];
#pragma unroll
    for (int i = 0; i < 2; ++i)
#pragma unroll
        for (int j = 0; j < 8; ++j) acc[i][j] = floatx4{0.f, 0.f, 0.f, 0.f};

    const int s4 = tid & 31;      // float4 index along s
    const int cg = tid >> 5;      // 0..7
    const float* xbase = x + ((size_t)n * 256) * 4096 + st * 128;
    unsigned int* ldsBdw = (unsigned int*)ldsB;

    for (int kc = 0; kc < 4; ++kc) {
        // --- async stage A: W1[mt*128..+128][kc*64..+64], xor seg swizzle
#pragma unroll
        for (int i = 0; i < 4; ++i) {
            int op = w * 4 + i;                 // 16 ops of 1KB
            int r = op * 8 + (lane >> 3);       // row 0..127
            int lseg = (lane & 7) ^ (r & 7);
            const u16* src = W1 + (size_t)(mt * 128 + r) * 256 + kc * 64 + lseg * 8;
            gld16(src, ldsA + op * 512);
        }
        // --- manual stage B: x[kc*64..+64][st*128..+128] -> ldsB[s][c] bf16 pairs
#pragma unroll
        for (int p = 0; p < 4; ++p) {
            int c0 = 2 * cg + 16 * p;           // even row in chunk
            const float4* r0 = (const float4*)(xbase + (size_t)(kc * 64 + c0) * 4096) + s4;
            const float4* r1 = (const float4*)(xbase + (size_t)(kc * 64 + c0 + 1) * 4096) + s4;
            float4 v0 = *r0, v1 = *r1;
            int cp = c0 >> 1, slog = cp >> 2, dwin = cp & 3;
#pragma unroll
            for (int j = 0; j < 4; ++j) {
                int s = 4 * s4 + j;
                unsigned int pk = (unsigned int)f2bf(((const float*)&v0)[j])
                                | ((unsigned int)f2bf(((const float*)&v1)[j]) << 16);
                ldsBdw[s * 32 + addsw(slog, s) * 4 + dwin] = pk;
            }
        }
        __syncthreads();

#pragma unroll
        for (int kk = 0; kk < 2; ++kk) {
            bf16x8 a[2];
#pragma unroll
            for (int mi = 0; mi < 2; ++mi) {
                int r = w * 32 + mi * 16 + l16;
                int phys = (kk * 4 + quad) ^ (r & 7);
                a[mi] = *(const bf16x8*)(ldsA + r * 64 + phys * 8);
            }
#pragma unroll
            for (int ni = 0; ni < 8; ++ni) {
                int s = ni * 16 + l16;
                int phys = addsw(kk * 4 + quad, s);
                bf16x8 b = *(const bf16x8*)(ldsB + s * 64 + phys * 8);
#pragma unroll
                for (int mi = 0; mi < 2; ++mi)
                    acc[mi][ni] = __builtin_amdgcn_mfma_f32_16x16x32_bf16(
                        a[mi], b, acc[mi][ni], 0, 0, 0);
            }
        }
        __syncthreads();
    }

#pragma unroll
    for (int mi = 0; mi < 2; ++mi)
#pragma unroll
        for (int r = 0; r < 4; ++r) {
            int oc = mt * 128 + w * 32 + mi * 16 + quad * 4 + r;
            float sh = shift1[oc];
#pragma unroll
            for (int ni = 0; ni < 8; ++ni) {
                int s = st * 128 + ni * 16 + l16;
                float val = acc[mi][ni][r] + sh;
                val = val > 0.f ? val : 0.f;
                tpg[((size_t)n * 384 + oc) * 4096 + s] = f2bf(val);
            }
        }
}

// --------------------------------------------------------------- gemm2 ----
// partials[n][kc][d][c] = sum_{s chunk} g[d][s]*phi[c][s]  (split-K=16)
__global__ __launch_bounds__(256) void gemm2_kernel(
    const u16* __restrict__ tpg, float* __restrict__ partials)
{
    const int kc = blockIdx.x, n = blockIdx.y;
    const int tid = threadIdx.x;
    const int wave = tid >> 6, lane = tid & 63;
    const int quad = lane >> 4, l16 = lane & 15;

    floatx4 acc[2][8];
#pragma unroll
    for (int i = 0; i < 2; ++i)
#pragma unroll
        for (int j = 0; j < 8; ++j) acc[i][j] = floatx4{0.f, 0.f, 0.f, 0.f};

    const u16* gbase = tpg + ((size_t)n * 384 + 256) * 4096;
    const u16* pbase = tpg + ((size_t)n * 384 + 128) * 4096;

#pragma unroll
    for (int kk = 0; kk < 8; ++kk) {
        int sb = kc * 256 + kk * 32 + quad * 8;
        bf16x8 a[2];
#pragma unroll
        for (int mi = 0; mi < 2; ++mi) {
            int d = wave * 32 + mi * 16 + l16;
            a[mi] = *reinterpret_cast<const bf16x8*>(gbase + (size_t)d * 4096 + sb);
        }
#pragma unroll
        for (int ci = 0; ci < 8; ++ci) {
            int cc = ci * 16 + l16;
            bf16x8 b = *reinterpret_cast<const bf16x8*>(pbase + (size_t)cc * 4096 + sb);
#pragma unroll
            for (int mi = 0; mi < 2; ++mi)
                acc[mi][ci] = __builtin_amdgcn_mfma_f32_16x16x32_bf16(
                    a[mi], b, acc[mi][ci], 0, 0, 0);
        }
    }

    float* outp = partials + (size_t)(n * 16 + kc) * 16384;
#pragma unroll
    for (int mi = 0; mi < 2; ++mi)
#pragma unroll
        for (int r = 0; r < 4; ++r) {
            int d = wave * 32 + mi * 16 + quad * 4 + r;
#pragma unroll
            for (int ci = 0; ci < 8; ++ci)
                outp[d * 128 + ci * 16 + l16] = acc[mi][ci][r];
        }
}

// ----------------------------------------------------------- kv reduce ----
__global__ __launch_bounds__(256) void kv_reduce_kernel(
    const float* __restrict__ partials, u16* __restrict__ kvT)
{
    int n = blockIdx.y;
    int idx = blockIdx.x * 256 + threadIdx.x;
    float s = 0.f;
#pragma unroll
    for (int kc = 0; kc < 16; ++kc)
        s += partials[(size_t)(n * 16 + kc) * 16384 + idx];
    kvT[(size_t)n * 16384 + idx] = f2bf(s);
}

// --------------------------------------------------------------- gemm3 ----
// out_sd[n][s][d] = sum_c theta[c][s] * kvT[d][c]; K=128 in 2 chunks of 64.
__global__ __launch_bounds__(256) void gemm3_kernel(
    const u16* __restrict__ tpg, const u16* __restrict__ kvT,
    u16* __restrict__ out_sd)
{
    const int st = blockIdx.x, n = blockIdx.y;
    const int tid = threadIdx.x;
    const int w = tid >> 6, lane = tid & 63;
    const int quad = lane >> 4, l16 = lane & 15;

    __shared__ __align__(16) u16 ldsT[128 * 64];  // theta^T [s][c], add-swizzled
    __shared__ __align__(16) u16 ldsK[128 * 64];  // kvT [d][c], xor-swizzled

    floatx4 acc[2][8];
#pragma unroll
    for (int i = 0; i < 2; ++i)
#pragma unroll
        for (int j = 0; j < 8; ++j) acc[i][j] = floatx4{0.f, 0.f, 0.f, 0.f};

    const int sl = tid & 15;      // 16B index along s
    const int cg = tid >> 4;      // 0..15
    const u16* tbase = tpg + (size_t)n * 384 * 4096 + st * 128;
    const u16* kbase = kvT + (size_t)n * 16384;
    unsigned int* ldsTdw = (unsigned int*)ldsT;

    for (int kc = 0; kc < 2; ++kc) {
        // --- async stage kvT chunk [d 0..127][kc*64..+64], xor swizzle
#pragma unroll
        for (int i = 0; i < 4; ++i) {
            int op = w * 4 + i;
            int r = op * 8 + (lane >> 3);
            int lseg = (lane & 7) ^ (r & 7);
            gld16(kbase + (size_t)r * 128 + kc * 64 + lseg * 8, ldsK + op * 512);
        }
        // --- manual stage theta^T chunk: rows c (pairs) -> ldsT[s][c]
#pragma unroll
        for (int p = 0; p < 2; ++p) {
            int c0 = 2 * cg + 32 * p;
            u16x8 t0 = *(const u16x8*)(tbase + (size_t)(kc * 64 + c0) * 4096 + 8 * sl);
            u16x8 t1 = *(const u16x8*)(tbase + (size_t)(kc * 64 + c0 + 1) * 4096 + 8 * sl);
            int cp = c0 >> 1, slog = cp >> 2, dwin = cp & 3;
#pragma unroll
            for (int j = 0; j < 8; ++j) {
                int s = 8 * sl + j;
                unsigned int pk = (unsigned int)t0[j] | ((unsigned int)t1[j] << 16);
                ldsTdw[s * 32 + addsw(slog, s) * 4 + dwin] = pk;
            }
        }
        __syncthreads();

#pragma unroll
        for (int kk = 0; kk < 2; ++kk) {
            bf16x8 a[2];
#pragma unroll
            for (int mi = 0; mi < 2; ++mi) {
                int s = w * 32 + mi * 16 + l16;
                int phys = addsw(kk * 4 + quad, s);
                a[mi] = *(const bf16x8*)(ldsT + s * 64 + phys * 8);
            }
#pragma unroll
            for (int di = 0; di < 8; ++di) {
                int d = di * 16 + l16;
                int phys = (kk * 4 + quad) ^ (d & 7);
                bf16x8 b = *(const bf16x8*)(ldsK + d * 64 + phys * 8);
#pragma unroll
                for (int mi = 0; mi < 2; ++mi)
                    acc[mi][di] = __builtin_amdgcn_mfma_f32_16x16x32_bf16(
                        a[mi], b, acc[mi][di], 0, 0, 0);
            }
        }
        __syncthreads();
    }

#pragma unroll
    for (int mi = 0; mi < 2; ++mi)
#pragma unroll
        for (int r = 0; r < 4; ++r) {
            int s = st * 128 + w * 32 + mi * 16 + quad * 4 + r;
#pragma unroll
            for (int di = 0; di < 8; ++di)
                out_sd[(size_t)n * 524288 + (size_t)s * 128 + di * 16 + l16] =
                    f2bf(acc[mi][di][r]);
        }
}

// --------------------------------------------------------------- gemm4 ----
// out[n][o][s2] = relu( sum_c2 Wz[o][c2]*y[c2][s2] + shift4[o] + x[n][o][s2] )
// y = out_sd viewed flat [128 c2][4096 s2].
__global__ __launch_bounds__(256) void gemm4_kernel(
    const u16* __restrict__ out_sd, const u16* __restrict__ Wz,
    const float* __restrict__ shift4, const float* __restrict__ x,
    float* __restrict__ out)
{
    const int st = blockIdx.x, ot = blockIdx.y, n = blockIdx.z;
    const int tid = threadIdx.x;
    const int w = tid >> 6, lane = tid & 63;
    const int quad = lane >> 4, l16 = lane & 15;

    __shared__ __align__(16) u16 ldsY[128 * 64];  // y^T [s2][c2], add-swizzled
    __shared__ __align__(16) u16 ldsW[128 * 64];  // Wz [o][c2], xor-swizzled

    floatx4 acc[2][8];
#pragma unroll
    for (int i = 0; i < 2; ++i)
#pragma unroll
        for (int j = 0; j < 8; ++j) acc[i][j] = floatx4{0.f, 0.f, 0.f, 0.f};

    const int sl = tid & 15;
    const int cg = tid >> 4;
    const u16* ybase = out_sd + (size_t)n * 524288 + st * 128;
    unsigned int* ldsYdw = (unsigned int*)ldsY;

    for (int kc = 0; kc < 2; ++kc) {
#pragma unroll
        for (int i = 0; i < 4; ++i) {
            int op = w * 4 + i;
            int r = op * 8 + (lane >> 3);
            int lseg = (lane & 7) ^ (r & 7);
            gld16(Wz + (size_t)(ot * 128 + r) * 128 + kc * 64 + lseg * 8, ldsW + op * 512);
        }
#pragma unroll
        for (int p = 0; p < 2; ++p) {
            int c0 = 2 * cg + 32 * p;
            u16x8 t0 = *(const u16x8*)(ybase + (size_t)(kc * 64 + c0) * 4096 + 8 * sl);
            u16x8 t1 = *(const u16x8*)(ybase + (size_t)(kc * 64 + c0 + 1) * 4096 + 8 * sl);
            int cp = c0 >> 1, slog = cp >> 2, dwin = cp & 3;
#pragma unroll
            for (int j = 0; j < 8; ++j) {
                int s = 8 * sl + j;
                unsigned int pk = (unsigned int)t0[j] | ((unsigned int)t1[j] << 16);
                ldsYdw[s * 32 + addsw(slog, s) * 4 + dwin] = pk;
            }
        }
        __syncthreads();

#pragma unroll
        for (int kk = 0; kk < 2; ++kk) {
            bf16x8 a[2];
#pragma unroll
            for (int mi = 0; mi < 2; ++mi) {
                int r = w * 32 + mi * 16 + l16;
                int phys = (kk * 4 + quad) ^ (r & 7);
                a[mi] = *(const bf16x8*)(ldsW + r * 64 + phys * 8);
            }
#pragma unroll
            for (int ni = 0; ni < 8; ++ni) {
                int s = ni * 16 + l16;
                int phys = addsw(kk * 4 + quad, s);
                bf16x8 b = *(const bf16x8*)(ldsY + s * 64 + phys * 8);
#pragma unroll
                for (int mi = 0; mi < 2; ++mi)
                    acc[mi][ni] = __builtin_amdgcn_mfma_f32_16x16x32_bf16(
                        a[mi], b, acc[mi][ni], 0, 0, 0);
            }
        }
        __syncthreads();
    }

#pragma unroll
    for (int mi = 0; mi < 2; ++mi)
#pragma unroll
        for (int r = 0; r < 4; ++r) {
            int o = ot * 128 + w * 32 + mi * 16 + quad * 4 + r;
            float sh = shift4[o];
#pragma unroll
            for (int ni = 0; ni < 8; ++ni) {
                int s2 = st * 128 + ni * 16 + l16;
                size_t idx = ((size_t)n * 256 + o) * 4096 + s2;
                float val = acc[mi][ni][r] + sh + x[idx];
                out[idx] = val > 0.f ? val : 0.f;
            }
        }
}

// -------------------------------------------------------------- launch ----
extern "C" void kernel_launch(void* const* d_in, const int* in_sizes, int n_in,
                              void* d_out, int out_size, void* d_ws, size_t ws_size,
                              hipStream_t stream)
{
    const float* x  = (const float*)d_in[0];
    const float* wt = (const float*)d_in[1];
    const float* wp = (const float*)d_in[2];
    const float* wg = (const float*)d_in[3];
    const float* wz = (const float*)d_in[4];
    const float* bn[16];
    for (int i = 0; i < 16; ++i) bn[i] = (const float*)d_in[5 + i];

    char* ws = (char*)d_ws;
    u16*   W1bf     = (u16*)  (ws + 0);
    float* shift1   = (float*)(ws + 196608);
    u16*   Wzbf     = (u16*)  (ws + 198144);
    float* shift4   = (float*)(ws + 263680);
    u16*   tpg      = (u16*)  (ws + 264704);
    float* partials = (float*)(ws + 50596352);
    u16*   kvT      = (u16*)  (ws + 67373568);
    u16*   out_sd   = (u16*)  (ws + 67897856);
    float* out = (float*)d_out;

    prep_kernel<<<384, 256, 0, stream>>>(
        wt, wp, wg, wz,
        bn[0], bn[1], bn[2], bn[3],
        bn[4], bn[5], bn[6], bn[7],
        bn[8], bn[9], bn[10], bn[11],
        bn[12], bn[13], bn[14], bn[15],
        W1bf, shift1, Wzbf, shift4);

    gemm1_kernel<<<dim3(32, 3, 16), 256, 0, stream>>>(x, W1bf, shift1, tpg);
    gemm2_kernel<<<dim3(16, 16), 256, 0, stream>>>(tpg, partials);
    kv_reduce_kernel<<<dim3(64, 16), 256, 0, stream>>>(partials, kvT);
    gemm3_kernel<<<dim3(32, 16), 256, 0, stream>>>(tpg, kvT, out_sd);
    gemm4_kernel<<<dim3(32, 2, 16), 256, 0, stream>>>(out_sd, Wzbf, shift4, x, out);
}

// Round 3
// 219.848 us; speedup vs baseline: 1.1301x; 1.0396x over previous
//
#include <hip/hip_runtime.h>

#define BN_EPS 1e-5f

typedef unsigned short u16;
typedef __bf16 bf16x8 __attribute__((ext_vector_type(8)));
typedef float floatx4 __attribute__((ext_vector_type(4)));
typedef u16 u16x4 __attribute__((ext_vector_type(4)));
typedef u16 u16x8 __attribute__((ext_vector_type(8)));

__device__ __forceinline__ u16 f2bf(float f) {
    union { float f; unsigned int u; } v; v.f = f;
    unsigned int r = (v.u + 0x7fffu + ((v.u >> 16) & 1u)) >> 16;
    return (u16)r;
}

// async 16B global->LDS; lane i lands at (wave-uniform) dst + i*16.
__device__ __forceinline__ void gld16(const void* gsrc, void* ldst) {
    __builtin_amdgcn_global_load_lds(
        (const __attribute__((address_space(1))) unsigned int*)gsrc,
        (__attribute__((address_space(3))) unsigned int*)ldst, 16, 0, 0);
}

// additive seg swizzle for transpose-staged [row][64] u16 tiles
__device__ __forceinline__ int addsw(int seg, int s) {
    return (seg + (s & 7) + ((s >> 3) & 7)) & 7;
}

// ---------------------------------------------------------------- prep ----
__global__ __launch_bounds__(256) void prep_kernel(
    const float* __restrict__ wt, const float* __restrict__ wp,
    const float* __restrict__ wg, const float* __restrict__ wz,
    const float* __restrict__ g1, const float* __restrict__ b1,
    const float* __restrict__ m1, const float* __restrict__ v1,
    const float* __restrict__ g2, const float* __restrict__ b2,
    const float* __restrict__ m2, const float* __restrict__ v2,
    const float* __restrict__ g3, const float* __restrict__ b3,
    const float* __restrict__ m3, const float* __restrict__ v3,
    const float* __restrict__ g4, const float* __restrict__ b4,
    const float* __restrict__ m4, const float* __restrict__ v4,
    u16* __restrict__ W1bf, float* __restrict__ shift1,
    u16* __restrict__ Wzbf, float* __restrict__ shift4)
{
    int id = blockIdx.x * 256 + threadIdx.x;
    if (id < 384 * 256) {
        int r = id >> 8, c = id & 255;
        int grp = r >> 7, ch = r & 127;
        const float* wsrc = grp == 0 ? wt : (grp == 1 ? wp : wg);
        const float* gg = grp == 0 ? g1 : (grp == 1 ? g2 : g3);
        const float* bb = grp == 0 ? b1 : (grp == 1 ? b2 : b3);
        const float* mm = grp == 0 ? m1 : (grp == 1 ? m2 : m3);
        const float* vv = grp == 0 ? v1 : (grp == 1 ? v2 : v3);
        float scale = gg[ch] * rsqrtf(vv[ch] + BN_EPS);
        W1bf[id] = f2bf(wsrc[ch * 256 + c] * scale);
        if (c == 0) shift1[r] = bb[ch] - mm[ch] * scale;
    }
    if (id < 256 * 128) {
        int o = id >> 7;
        float scale = g4[o] * rsqrtf(v4[o] + BN_EPS);
        Wzbf[id] = f2bf(wz[id] * scale);
        if ((id & 127) == 0) shift4[o] = b4[o] - m4[o] * scale;
    }
}

// --------------------------------------------------------------- gemm1 ----
// mt=0: theta -> theta_sm[n][s][c] (s-major);  mt=1: phi -> pg rows 0..127;
// mt=2: g -> pg rows 128..255.  x loads software-pipelined across kc.
__global__ __launch_bounds__(256) void gemm1_kernel(
    const float* __restrict__ x, const u16* __restrict__ W1,
    const float* __restrict__ shift1,
    u16* __restrict__ theta_sm, u16* __restrict__ pg)
{
    const int st = blockIdx.x, mt = blockIdx.y, n = blockIdx.z;
    const int tid = threadIdx.x;
    const int w = tid >> 6, lane = tid & 63;
    const int quad = lane >> 4, l16 = lane & 15;

    __shared__ __align__(16) u16 ldsA[128 * 64];  // W1 chunk, xor-swizzled
    __shared__ __align__(16) u16 ldsB[128 * 64];  // x^T chunk [s][c], add-swizzled

    floatx4 acc[2][8];
#pragma unroll
    for (int i = 0; i < 2; ++i)
#pragma unroll
        for (int j = 0; j < 8; ++j) acc[i][j] = floatx4{0.f, 0.f, 0.f, 0.f};

    const int s4 = tid & 31;      // float4 index along s
    const int cg = tid >> 5;      // 0..7
    const float* xbase = x + ((size_t)n * 256) * 4096 + st * 128;
    unsigned int* ldsBdw = (unsigned int*)ldsB;

    float4 xv0[4], xv1[4];
#pragma unroll
    for (int p = 0; p < 4; ++p) {
        int c0 = 2 * cg + 16 * p;
        xv0[p] = *((const float4*)(xbase + (size_t)c0 * 4096) + s4);
        xv1[p] = *((const float4*)(xbase + (size_t)(c0 + 1) * 4096) + s4);
    }

    for (int kc = 0; kc < 4; ++kc) {
        // --- write B tile from prefetched regs (bf16 pairs, add-swizzled)
#pragma unroll
        for (int p = 0; p < 4; ++p) {
            int cp = cg + 8 * p, slog = cp >> 2, dwin = cp & 3;
#pragma unroll
            for (int j = 0; j < 4; ++j) {
                int s = 4 * s4 + j;
                unsigned int pk = (unsigned int)f2bf(((const float*)&xv0[p])[j])
                                | ((unsigned int)f2bf(((const float*)&xv1[p])[j]) << 16);
                ldsBdw[s * 32 + addsw(slog, s) * 4 + dwin] = pk;
            }
        }
        // --- async stage A: W1[mt*128..+128][kc*64..+64], xor seg swizzle
#pragma unroll
        for (int i = 0; i < 4; ++i) {
            int op = w * 4 + i;
            int r = op * 8 + (lane >> 3);
            int lseg = (lane & 7) ^ (r & 7);
            gld16(W1 + (size_t)(mt * 128 + r) * 256 + kc * 64 + lseg * 8,
                  ldsA + op * 512);
        }
        // --- prefetch next x chunk (drains with gld16 at the barrier)
        if (kc < 3) {
#pragma unroll
            for (int p = 0; p < 4; ++p) {
                int c0 = 2 * cg + 16 * p;
                xv0[p] = *((const float4*)(xbase + (size_t)((kc + 1) * 64 + c0) * 4096) + s4);
                xv1[p] = *((const float4*)(xbase + (size_t)((kc + 1) * 64 + c0 + 1) * 4096) + s4);
            }
        }
        __syncthreads();

#pragma unroll
        for (int kk = 0; kk < 2; ++kk) {
            bf16x8 a[2];
#pragma unroll
            for (int mi = 0; mi < 2; ++mi) {
                int r = w * 32 + mi * 16 + l16;
                int phys = (kk * 4 + quad) ^ (r & 7);
                a[mi] = *(const bf16x8*)(ldsA + r * 64 + phys * 8);
            }
#pragma unroll
            for (int ni = 0; ni < 8; ++ni) {
                int s = ni * 16 + l16;
                int phys = addsw(kk * 4 + quad, s);
                bf16x8 b = *(const bf16x8*)(ldsB + s * 64 + phys * 8);
#pragma unroll
                for (int mi = 0; mi < 2; ++mi)
                    acc[mi][ni] = __builtin_amdgcn_mfma_f32_16x16x32_bf16(
                        a[mi], b, acc[mi][ni], 0, 0, 0);
            }
        }
        __syncthreads();
    }

    if (mt == 0) {
        // theta: write s-major [s][c], 8B vectorized (oc contiguous over r)
#pragma unroll
        for (int mi = 0; mi < 2; ++mi) {
            int ocb = w * 32 + mi * 16 + quad * 4;
            float sh0 = shift1[ocb + 0], sh1 = shift1[ocb + 1];
            float sh2 = shift1[ocb + 2], sh3 = shift1[ocb + 3];
#pragma unroll
            for (int ni = 0; ni < 8; ++ni) {
                int s = st * 128 + ni * 16 + l16;
                float v0 = acc[mi][ni][0] + sh0, v1 = acc[mi][ni][1] + sh1;
                float v2 = acc[mi][ni][2] + sh2, v3 = acc[mi][ni][3] + sh3;
                u16x4 pk;
                pk[0] = f2bf(v0 > 0.f ? v0 : 0.f);
                pk[1] = f2bf(v1 > 0.f ? v1 : 0.f);
                pk[2] = f2bf(v2 > 0.f ? v2 : 0.f);
                pk[3] = f2bf(v3 > 0.f ? v3 : 0.f);
                *(u16x4*)(theta_sm + (size_t)n * 524288 + (size_t)s * 128 + ocb) = pk;
            }
        }
    } else {
        // phi/g: row-major [oc'][s]
#pragma unroll
        for (int mi = 0; mi < 2; ++mi)
#pragma unroll
            for (int r = 0; r < 4; ++r) {
                int oc = mt * 128 + w * 32 + mi * 16 + quad * 4 + r;
                int prow = (mt - 1) * 128 + w * 32 + mi * 16 + quad * 4 + r;
                float sh = shift1[oc];
#pragma unroll
                for (int ni = 0; ni < 8; ++ni) {
                    int s = st * 128 + ni * 16 + l16;
                    float val = acc[mi][ni][r] + sh;
                    val = val > 0.f ? val : 0.f;
                    pg[(size_t)n * 1048576 + (size_t)prow * 4096 + s] = f2bf(val);
                }
            }
    }
}

// --------------------------------------------------------------- gemm2 ----
// partials[n][kc][d][c] = sum_{s chunk} g[d][s]*phi[c][s]  (split-K=16)
// 512 threads (8 waves); gld16 staging of both operands.
__global__ __launch_bounds__(512) void gemm2_kernel(
    const u16* __restrict__ pg, float* __restrict__ partials)
{
    const int kc = blockIdx.x, n = blockIdx.y;
    const int tid = threadIdx.x;
    const int w = tid >> 6, lane = tid & 63;
    const int quad = lane >> 4, l16 = lane & 15;

    __shared__ __align__(16) u16 ldsG[128 * 64];  // g rows, xor-swizzled
    __shared__ __align__(16) u16 ldsP[128 * 64];  // phi rows, xor-swizzled

    floatx4 acc[2][4];
#pragma unroll
    for (int i = 0; i < 2; ++i)
#pragma unroll
        for (int j = 0; j < 4; ++j) acc[i][j] = floatx4{0.f, 0.f, 0.f, 0.f};

    const int d0 = (w >> 1) * 32, c0 = (w & 1) * 64;
    const u16* base = pg + (size_t)n * 1048576;   // phi rows 0..127, g 128..255

    for (int ch = 0; ch < 4; ++ch) {
        int s0 = kc * 256 + ch * 64;
#pragma unroll
        for (int i = 0; i < 2; ++i) {
            int op = w * 2 + i;
            int r = op * 8 + (lane >> 3);
            int lseg = (lane & 7) ^ (r & 7);
            gld16(base + (size_t)(128 + r) * 4096 + s0 + lseg * 8, ldsG + op * 512);
            gld16(base + (size_t)r * 4096 + s0 + lseg * 8, ldsP + op * 512);
        }
        __syncthreads();

#pragma unroll
        for (int kk = 0; kk < 2; ++kk) {
            bf16x8 a[2];
#pragma unroll
            for (int mi = 0; mi < 2; ++mi) {
                int r = d0 + mi * 16 + l16;
                int phys = (kk * 4 + quad) ^ (r & 7);
                a[mi] = *(const bf16x8*)(ldsG + r * 64 + phys * 8);
            }
#pragma unroll
            for (int ci = 0; ci < 4; ++ci) {
                int r = c0 + ci * 16 + l16;
                int phys = (kk * 4 + quad) ^ (r & 7);
                bf16x8 b = *(const bf16x8*)(ldsP + r * 64 + phys * 8);
#pragma unroll
                for (int mi = 0; mi < 2; ++mi)
                    acc[mi][ci] = __builtin_amdgcn_mfma_f32_16x16x32_bf16(
                        a[mi], b, acc[mi][ci], 0, 0, 0);
            }
        }
        __syncthreads();
    }

    float* outp = partials + (size_t)(n * 16 + kc) * 16384;
#pragma unroll
    for (int mi = 0; mi < 2; ++mi)
#pragma unroll
        for (int r = 0; r < 4; ++r) {
            int d = d0 + mi * 16 + quad * 4 + r;
#pragma unroll
            for (int ci = 0; ci < 4; ++ci)
                outp[d * 128 + c0 + ci * 16 + l16] = acc[mi][ci][r];
        }
}

// ----------------------------------------------------------- kv reduce ----
__global__ __launch_bounds__(256) void kv_reduce_kernel(
    const float* __restrict__ partials, u16* __restrict__ kvT)
{
    int n = blockIdx.y;
    int f4 = blockIdx.x * 256 + threadIdx.x;    // 0..4095
    const float4* p4 = (const float4*)partials;
    float4 s = {0.f, 0.f, 0.f, 0.f};
#pragma unroll
    for (int kc = 0; kc < 16; ++kc) {
        float4 v = p4[(size_t)(n * 16 + kc) * 4096 + f4];
        s.x += v.x; s.y += v.y; s.z += v.z; s.w += v.w;
    }
    u16x4 o; o[0] = f2bf(s.x); o[1] = f2bf(s.y); o[2] = f2bf(s.z); o[3] = f2bf(s.w);
    *(u16x4*)(kvT + (size_t)n * 16384 + f4 * 4) = o;
}

// --------------------------------------------------------------- gemm3 ----
// out_sd[n][s][d] = sum_c theta_sm[s][c] * kvT[d][c] — both k-major, pure gld16.
__global__ __launch_bounds__(256) void gemm3_kernel(
    const u16* __restrict__ theta_sm, const u16* __restrict__ kvT,
    u16* __restrict__ out_sd)
{
    const int st = blockIdx.x, n = blockIdx.y;
    const int tid = threadIdx.x;
    const int w = tid >> 6, lane = tid & 63;
    const int quad = lane >> 4, l16 = lane & 15;

    __shared__ __align__(16) u16 ldsT[128 * 64];  // theta [s][c], xor-swizzled
    __shared__ __align__(16) u16 ldsK[128 * 64];  // kvT [d][c], xor-swizzled

    floatx4 acc[2][8];
#pragma unroll
    for (int i = 0; i < 2; ++i)
#pragma unroll
        for (int j = 0; j < 8; ++j) acc[i][j] = floatx4{0.f, 0.f, 0.f, 0.f};

    const u16* tbase = theta_sm + (size_t)n * 524288 + (size_t)st * 128 * 128;
    const u16* kbase = kvT + (size_t)n * 16384;

    for (int ch = 0; ch < 2; ++ch) {
#pragma unroll
        for (int i = 0; i < 4; ++i) {
            int op = w * 4 + i;
            int r = op * 8 + (lane >> 3);
            int lseg = (lane & 7) ^ (r & 7);
            gld16(tbase + (size_t)r * 128 + ch * 64 + lseg * 8, ldsT + op * 512);
            gld16(kbase + (size_t)r * 128 + ch * 64 + lseg * 8, ldsK + op * 512);
        }
        __syncthreads();

#pragma unroll
        for (int kk = 0; kk < 2; ++kk) {
            bf16x8 a[2];
#pragma unroll
            for (int mi = 0; mi < 2; ++mi) {
                int r = w * 32 + mi * 16 + l16;
                int phys = (kk * 4 + quad) ^ (r & 7);
                a[mi] = *(const bf16x8*)(ldsT + r * 64 + phys * 8);
            }
#pragma unroll
            for (int di = 0; di < 8; ++di) {
                int r = di * 16 + l16;
                int phys = (kk * 4 + quad) ^ (r & 7);
                bf16x8 b = *(const bf16x8*)(ldsK + r * 64 + phys * 8);
#pragma unroll
                for (int mi = 0; mi < 2; ++mi)
                    acc[mi][di] = __builtin_amdgcn_mfma_f32_16x16x32_bf16(
                        a[mi], b, acc[mi][di], 0, 0, 0);
            }
        }
        __syncthreads();
    }

#pragma unroll
    for (int mi = 0; mi < 2; ++mi)
#pragma unroll
        for (int r = 0; r < 4; ++r) {
            int s = st * 128 + w * 32 + mi * 16 + quad * 4 + r;
#pragma unroll
            for (int di = 0; di < 8; ++di)
                out_sd[(size_t)n * 524288 + (size_t)s * 128 + di * 16 + l16] =
                    f2bf(acc[mi][di][r]);
        }
}

// --------------------------------------------------------------- gemm4 ----
// out[n][o][s2] = relu( sum_c2 Wz[o][c2]*y[c2][s2] + shift4[o] + x[n][o][s2] )
// y = out_sd viewed flat [128 c2][4096 s2]; y loads software-pipelined.
__global__ __launch_bounds__(256) void gemm4_kernel(
    const u16* __restrict__ out_sd, const u16* __restrict__ Wz,
    const float* __restrict__ shift4, const float* __restrict__ x,
    float* __restrict__ out)
{
    const int st = blockIdx.x, ot = blockIdx.y, n = blockIdx.z;
    const int tid = threadIdx.x;
    const int w = tid >> 6, lane = tid & 63;
    const int quad = lane >> 4, l16 = lane & 15;

    __shared__ __align__(16) u16 ldsY[128 * 64];  // y^T [s2][c2], add-swizzled
    __shared__ __align__(16) u16 ldsW[128 * 64];  // Wz [o][c2], xor-swizzled

    floatx4 acc[2][8];
#pragma unroll
    for (int i = 0; i < 2; ++i)
#pragma unroll
        for (int j = 0; j < 8; ++j) acc[i][j] = floatx4{0.f, 0.f, 0.f, 0.f};

    const int sl = tid & 15;
    const int cg = tid >> 4;
    const u16* ybase = out_sd + (size_t)n * 524288 + st * 128;
    unsigned int* ldsYdw = (unsigned int*)ldsY;

    u16x8 yv0[2], yv1[2];
#pragma unroll
    for (int p = 0; p < 2; ++p) {
        int c0 = 2 * cg + 32 * p;
        yv0[p] = *(const u16x8*)(ybase + (size_t)c0 * 4096 + 8 * sl);
        yv1[p] = *(const u16x8*)(ybase + (size_t)(c0 + 1) * 4096 + 8 * sl);
    }

    for (int kc = 0; kc < 2; ++kc) {
#pragma unroll
        for (int p = 0; p < 2; ++p) {
            int cp = cg + 16 * p, slog = cp >> 2, dwin = cp & 3;
#pragma unroll
            for (int j = 0; j < 8; ++j) {
                int s = 8 * sl + j;
                unsigned int pk = (unsigned int)yv0[p][j] | ((unsigned int)yv1[p][j] << 16);
                ldsYdw[s * 32 + addsw(slog, s) * 4 + dwin] = pk;
            }
        }
#pragma unroll
        for (int i = 0; i < 4; ++i) {
            int op = w * 4 + i;
            int r = op * 8 + (lane >> 3);
            int lseg = (lane & 7) ^ (r & 7);
            gld16(Wz + (size_t)(ot * 128 + r) * 128 + kc * 64 + lseg * 8, ldsW + op * 512);
        }
        if (kc < 1) {
#pragma unroll
            for (int p = 0; p < 2; ++p) {
                int c0 = 2 * cg + 32 * p;
                yv0[p] = *(const u16x8*)(ybase + (size_t)(64 + c0) * 4096 + 8 * sl);
                yv1[p] = *(const u16x8*)(ybase + (size_t)(64 + c0 + 1) * 4096 + 8 * sl);
            }
        }
        __syncthreads();

#pragma unroll
        for (int kk = 0; kk < 2; ++kk) {
            bf16x8 a[2];
#pragma unroll
            for (int mi = 0; mi < 2; ++mi) {
                int r = w * 32 + mi * 16 + l16;
                int phys = (kk * 4 + quad) ^ (r & 7);
                a[mi] = *(const bf16x8*)(ldsW + r * 64 + phys * 8);
            }
#pragma unroll
            for (int ni = 0; ni < 8; ++ni) {
                int s = ni * 16 + l16;
                int phys = addsw(kk * 4 + quad, s);
                bf16x8 b = *(const bf16x8*)(ldsY + s * 64 + phys * 8);
#pragma unroll
                for (int mi = 0; mi < 2; ++mi)
                    acc[mi][ni] = __builtin_amdgcn_mfma_f32_16x16x32_bf16(
                        a[mi], b, acc[mi][ni], 0, 0, 0);
            }
        }
        __syncthreads();
    }

#pragma unroll
    for (int mi = 0; mi < 2; ++mi)
#pragma unroll
        for (int r = 0; r < 4; ++r) {
            int o = ot * 128 + w * 32 + mi * 16 + quad * 4 + r;
            float sh = shift4[o];
#pragma unroll
            for (int ni = 0; ni < 8; ++ni) {
                int s2 = st * 128 + ni * 16 + l16;
                size_t idx = ((size_t)n * 256 + o) * 4096 + s2;
                float val = acc[mi][ni][r] + sh + x[idx];
                out[idx] = val > 0.f ? val : 0.f;
            }
        }
}

// -------------------------------------------------------------- launch ----
extern "C" void kernel_launch(void* const* d_in, const int* in_sizes, int n_in,
                              void* d_out, int out_size, void* d_ws, size_t ws_size,
                              hipStream_t stream)
{
    const float* x  = (const float*)d_in[0];
    const float* wt = (const float*)d_in[1];
    const float* wp = (const float*)d_in[2];
    const float* wg = (const float*)d_in[3];
    const float* wz = (const float*)d_in[4];
    const float* bn[16];
    for (int i = 0; i < 16; ++i) bn[i] = (const float*)d_in[5 + i];

    char* ws = (char*)d_ws;
    u16*   W1bf     = (u16*)  (ws + 0);          // 196608
    float* shift1   = (float*)(ws + 196608);     // 1536
    u16*   Wzbf     = (u16*)  (ws + 198144);     // 65536
    float* shift4   = (float*)(ws + 263680);     // 1024
    u16*   theta_sm = (u16*)  (ws + 264704);     // 16*4096*128*2 = 16777216
    u16*   pg       = (u16*)  (ws + 17041920);   // 16*256*4096*2 = 33554432
    float* partials = (float*)(ws + 50596352);   // 16*16*16384*4 = 16777216
    u16*   kvT      = (u16*)  (ws + 67373568);   // 524288
    u16*   out_sd   = (u16*)  (ws + 67897856);   // 16777216 (end 84.7MB)
    float* out = (float*)d_out;

    prep_kernel<<<384, 256, 0, stream>>>(
        wt, wp, wg, wz,
        bn[0], bn[1], bn[2], bn[3],
        bn[4], bn[5], bn[6], bn[7],
        bn[8], bn[9], bn[10], bn[11],
        bn[12], bn[13], bn[14], bn[15],
        W1bf, shift1, Wzbf, shift4);

    gemm1_kernel<<<dim3(32, 3, 16), 256, 0, stream>>>(x, W1bf, shift1, theta_sm, pg);
    gemm2_kernel<<<dim3(16, 16), 512, 0, stream>>>(pg, partials);
    kv_reduce_kernel<<<dim3(16, 16), 256, 0, stream>>>(partials, kvT);
    gemm3_kernel<<<dim3(32, 16), 256, 0, stream>>>(theta_sm, kvT, out_sd);
    gemm4_kernel<<<dim3(32, 2, 16), 256, 0, stream>>>(out_sd, Wzbf, shift4, x, out);
}